// Round 3
// baseline (548.532 us; speedup 1.0000x reference)
//
#include <hip/hip_runtime.h>
#include <math.h>

// critic_attention, round 3: one fused kernel, two phases.
//
// Phase A (attention): wave = 16 items x 4 agent-groups. Lane l: item = l&15,
//   group q = l>>4 handles agents {4q..4q+3}. Weights wave-uniform -> s_load.
//   Group 0 computes agent 0 (self) -> x_self stored to LDS tile + a_self
//   broadcast by shfl. Online softmax per lane over its 3-4 agents, then a
//   2-step shfl_xor butterfly merges (m, s, xsum[64]) across the 4 groups.
//   262144 threads total = 4096 waves = 3-4 waves/SIMD (vs round 1's 1).
//
// Phase B (MLP): lane = item, classic LDS-tiled GEMM. x_cat tile [64][129]
//   (odd stride -> 2-way bank alias = free). Wave w computes output columns
//   [32w, 32w+32) of W2 then W3 (x1 overwrites tile in place between
//   barriers), Wc partials reduced through a tiny LDS array.

#define SLOPE 0.01f
#define LOG2E 1.4426950408889634f

__device__ __forceinline__ float lrelu(float x) { return fmaxf(x, SLOPE * x); }

__device__ __forceinline__ float fast_tanh(float x) {
    float e = exp2f(x * (2.0f * LOG2E));
    return 1.0f - __fdividef(2.0f, e + 1.0f);
}

// h[c] = b0[c] + sum_f x[f] * W0[f][c]   (40 features: 32 obs + 8 act)
__device__ __forceinline__ void layer0(float h[64], const float* __restrict__ ox,
                                       const float* __restrict__ ax,
                                       const float* __restrict__ W0,
                                       const float* __restrict__ b0) {
#pragma unroll
    for (int c = 0; c < 64; ++c) h[c] = b0[c];
#pragma unroll
    for (int f4 = 0; f4 < 8; ++f4) {
        float4 xv = *reinterpret_cast<const float4*>(ox + f4 * 4);
        const float* w = W0 + f4 * 256;
#pragma unroll
        for (int c = 0; c < 64; ++c) {
            h[c] = fmaf(xv.x, w[c], h[c]);
            h[c] = fmaf(xv.y, w[c + 64], h[c]);
            h[c] = fmaf(xv.z, w[c + 128], h[c]);
            h[c] = fmaf(xv.w, w[c + 192], h[c]);
        }
    }
#pragma unroll
    for (int f4 = 0; f4 < 2; ++f4) {
        float4 xv = *reinterpret_cast<const float4*>(ax + f4 * 4);
        const float* w = W0 + 2048 + f4 * 256;
#pragma unroll
        for (int c = 0; c < 64; ++c) {
            h[c] = fmaf(xv.x, w[c], h[c]);
            h[c] = fmaf(xv.y, w[c + 64], h[c]);
            h[c] = fmaf(xv.z, w[c + 128], h[c]);
            h[c] = fmaf(xv.w, w[c + 192], h[c]);
        }
    }
}

// in-place tanh of h, returns dot(tanh(h), W1o[0..63])
__device__ __forceinline__ float tanh_dot(float h[64], const float* __restrict__ W1o) {
    float d0 = 0.f, d1 = 0.f, d2 = 0.f, d3 = 0.f;
#pragma unroll
    for (int c = 0; c < 64; c += 4) {
        h[c + 0] = fast_tanh(h[c + 0]);
        h[c + 1] = fast_tanh(h[c + 1]);
        h[c + 2] = fast_tanh(h[c + 2]);
        h[c + 3] = fast_tanh(h[c + 3]);
        d0 = fmaf(h[c + 0], W1o[c + 0], d0);
        d1 = fmaf(h[c + 1], W1o[c + 1], d1);
        d2 = fmaf(h[c + 2], W1o[c + 2], d2);
        d3 = fmaf(h[c + 3], W1o[c + 3], d3);
    }
    return (d0 + d1) + (d2 + d3);
}

__global__ __launch_bounds__(256, 3) void critic_attention_kernel(
    const float* __restrict__ obs, const float* __restrict__ act,
    const float* __restrict__ W0, const float* __restrict__ b0,
    const float* __restrict__ W1, const float* __restrict__ b1v,
    const float* __restrict__ W2, const float* __restrict__ b2,
    const float* __restrict__ W3, const float* __restrict__ b3,
    const float* __restrict__ Wc, const float* __restrict__ bcv,
    float* __restrict__ out)
{
    __shared__ float tile[64 * 129];  // x_cat, then x1 in place
    __shared__ float red[64 * 5];     // Wc partials

    const int t = threadIdx.x;
    const int lane = t & 63;
    const int wq = t >> 6;       // wave 0..3
    const int iw = lane & 15;    // item within wave (phase A)
    const int q  = lane >> 4;    // agent group 0..3 (phase A)
    const int rowA = wq * 16 + iw;

    const long itemA = (long)blockIdx.x * 64 + rowA;
    const float* orow = obs + itemA * 512;
    const float* arow = act + itemA * 128;

    float h[64], xsum[64];
    float m, s;

    // ---------------- phase A: first agent of each group (q0 -> agent 0) ----------------
    layer0(h, orow + (q * 4) * 32, arow + (q * 4) * 8, W0, b0);

    float a_self_v = 0.f, d_first = 0.f;
    if (q == 0) {
        float a0 = 0.f, a1 = 0.f, a2 = 0.f, a3 = 0.f;
#pragma unroll
        for (int c = 0; c < 64; c += 4) {
            float s0 = lrelu(h[c + 0]);
            float s1 = lrelu(h[c + 1]);
            float s2 = lrelu(h[c + 2]);
            float s3 = lrelu(h[c + 3]);
            tile[rowA * 129 + c + 0] = s0;     // x_cat[0:64] = x_self
            tile[rowA * 129 + c + 1] = s1;
            tile[rowA * 129 + c + 2] = s2;
            tile[rowA * 129 + c + 3] = s3;
            a0 = fmaf(s0, W1[c + 0], a0);
            a1 = fmaf(s1, W1[c + 1], a1);
            a2 = fmaf(s2, W1[c + 2], a2);
            a3 = fmaf(s3, W1[c + 3], a3);
        }
        a_self_v = b1v[0] + ((a0 + a1) + (a2 + a3));
    } else {
        d_first = tanh_dot(h, W1 + 64);
    }
    const float a_self = __shfl(a_self_v, iw, 64);   // from the q==0 lane of this item

    if (q == 0) {
        m = -INFINITY; s = 0.f;
#pragma unroll
        for (int c = 0; c < 64; ++c) xsum[c] = 0.f;
    } else {
        float l0 = lrelu(a_self + d_first);
        m = l0; s = 1.f;
#pragma unroll
        for (int c = 0; c < 64; ++c) xsum[c] = h[c];
    }

    // remaining 3 agents per group (q0: agents 1,2,3 -> all 15 others covered)
    for (int k = 1; k < 4; ++k) {
        const int ag = q * 4 + k;
        layer0(h, orow + ag * 32, arow + ag * 8, W0, b0);
        float d = tanh_dot(h, W1 + 64);
        float l0 = lrelu(a_self + d);
        float mn = fmaxf(m, l0);
        float f = exp2f((m - mn) * LOG2E);
        float e = exp2f((l0 - mn) * LOG2E);
        s = fmaf(s, f, e);
        m = mn;
#pragma unroll
        for (int c = 0; c < 64; ++c) xsum[c] = fmaf(xsum[c], f, e * h[c]);
    }

    // ---------------- butterfly merge across the 4 groups (lanes ^16, ^32) ----------------
#pragma unroll
    for (int mask = 16; mask <= 32; mask <<= 1) {
        float mo = __shfl_xor(m, mask, 64);
        float so = __shfl_xor(s, mask, 64);
        float M = fmaxf(m, mo);
        float f1 = exp2f((m - M) * LOG2E);   // exp2(-inf)=0 handles q0's empty init
        float f2 = exp2f((mo - M) * LOG2E);
        s = s * f1 + so * f2;
        m = M;
#pragma unroll
        for (int c = 0; c < 64; ++c) {
            float xo = __shfl_xor(xsum[c], mask, 64);
            xsum[c] = xsum[c] * f1 + xo * f2;
        }
    }

    const float inv = __fdividef(1.0f, s);
    if (q == 1) {
#pragma unroll
        for (int c = 0; c < 32; ++c) tile[rowA * 129 + 64 + c] = xsum[c] * inv;
    } else if (q == 2) {
#pragma unroll
        for (int c = 0; c < 32; ++c) tile[rowA * 129 + 96 + c] = xsum[32 + c] * inv;
    }
    __syncthreads();

    // ---------------- phase B: lane = item, wave wq owns cols [32wq, 32wq+32) ----------------
    const int jb = wq * 32;
    float acc[32];

    // x1 = lrelu(x_cat @ W2 + b2)
#pragma unroll
    for (int jj = 0; jj < 32; ++jj) acc[jj] = b2[jb + jj];
#pragma unroll 8
    for (int i = 0; i < 128; ++i) {
        float xv = tile[lane * 129 + i];
        const float* wr = W2 + i * 128 + jb;
#pragma unroll
        for (int jj = 0; jj < 32; ++jj) acc[jj] = fmaf(xv, wr[jj], acc[jj]);
    }
    __syncthreads();   // all x_cat reads done
#pragma unroll
    for (int jj = 0; jj < 32; ++jj) tile[lane * 129 + jb + jj] = lrelu(acc[jj]);
    __syncthreads();

    // x2 = lrelu(x1 @ W3 + b3), then Wc partial
#pragma unroll
    for (int jj = 0; jj < 32; ++jj) acc[jj] = b3[jb + jj];
#pragma unroll 8
    for (int i = 0; i < 128; ++i) {
        float xv = tile[lane * 129 + i];
        const float* wr = W3 + i * 128 + jb;
#pragma unroll
        for (int jj = 0; jj < 32; ++jj) acc[jj] = fmaf(xv, wr[jj], acc[jj]);
    }

    float v0 = 0.f, v1 = 0.f, v2 = 0.f, v3 = 0.f;
#pragma unroll
    for (int jj = 0; jj < 32; jj += 4) {
        v0 = fmaf(lrelu(acc[jj + 0]), Wc[jb + jj + 0], v0);
        v1 = fmaf(lrelu(acc[jj + 1]), Wc[jb + jj + 1], v1);
        v2 = fmaf(lrelu(acc[jj + 2]), Wc[jb + jj + 2], v2);
        v3 = fmaf(lrelu(acc[jj + 3]), Wc[jb + jj + 3], v3);
    }
    red[lane * 5 + wq] = (v0 + v1) + (v2 + v3);
    __syncthreads();
    if (wq == 0) {
        out[(long)blockIdx.x * 64 + lane] =
            bcv[0] + ((red[lane * 5 + 0] + red[lane * 5 + 1]) +
                      (red[lane * 5 + 2] + red[lane * 5 + 3]));
    }
}

extern "C" void kernel_launch(void* const* d_in, const int* in_sizes, int n_in,
                              void* d_out, int out_size, void* d_ws, size_t ws_size,
                              hipStream_t stream) {
    (void)in_sizes; (void)n_in; (void)d_ws; (void)ws_size; (void)out_size;
    const float* obs = (const float*)d_in[0];
    const float* act = (const float*)d_in[1];
    const float* W0  = (const float*)d_in[2];
    const float* b0  = (const float*)d_in[3];
    const float* W1  = (const float*)d_in[4];
    const float* b1  = (const float*)d_in[5];
    const float* W2  = (const float*)d_in[6];
    const float* b2  = (const float*)d_in[7];
    const float* W3  = (const float*)d_in[8];
    const float* b3  = (const float*)d_in[9];
    const float* Wc  = (const float*)d_in[10];
    const float* bc  = (const float*)d_in[11];

    critic_attention_kernel<<<dim3(65536 / 64), dim3(256), 0, stream>>>(
        obs, act, W0, b0, W1, b1, W2, b2, W3, b3, Wc, bc, (float*)d_out);
}